// Round 4
// baseline (543.527 us; speedup 1.0000x reference)
//
#include <hip/hip_runtime.h>
#include <math.h>

// Problem constants (setup_inputs: block_size=2048, embedding_dim=256)
#define PB 2048
#define PD 256
// K = D/2 - 1 = 127. Nonzeros per position p: diag cos at (2j,2j) j=0..127
// (j=127 reuses theta_126), -sin at (2j,2j+2), sin at (2j+2,2j) for j=0..126.
// Everything else is exactly 0 -> bulk-zero via hipMemsetAsync (rides the
// 6.2 TB/s fillBufferAligned path measured on this box), then scatter ~782k
// nonzero floats with a tiny kernel.

// theta_i = 10000^(-2*(i-1)/D)  [the (i-1) quirk is intentional, per reference]
//         = exp2( -(i-1) * 2*log2(10000)/256 )
__device__ __forceinline__ float theta_of(int i) {
    const float c = 0.10381025187f; // 2*log2(10000)/256
    return exp2f(-(float)(i - 1) * c);
}

// One thread per (p, j): p = position (0..2047), j = 0..127.
//   row = 2j; diag (row,row) = cos(p * theta_min(j,126))
//   if j<=126: (row, row+2) = -sin(p*theta_j); (row+2, row) = sin(p*theta_j)
__global__ __launch_bounds__(256) void rope_scatter_kernel(float* __restrict__ out) {
    unsigned int t = blockIdx.x * blockDim.x + threadIdx.x; // < 262144
    int j = (int)(t & 127u);
    int p = (int)(t >> 7);

    float fp = (float)p;
    int jj = j < 126 ? j : 126;
    float c = cosf(fp * theta_of(jj));

    float* base = out + (size_t)p * (PD * PD);
    int row = 2 * j;
    base[(size_t)row * PD + row] = c; // diagonal

    if (j <= 126) {
        float s = sinf(fp * theta_of(j));
        base[(size_t)row * PD + row + 2] = -s;
        base[(size_t)(row + 2) * PD + row] = s;
    }
}

extern "C" void kernel_launch(void* const* d_in, const int* in_sizes, int n_in,
                              void* d_out, int out_size, void* d_ws, size_t ws_size,
                              hipStream_t stream) {
    (void)d_in; (void)in_sizes; (void)n_in; (void)d_ws; (void)ws_size;
    float* out = (float*)d_out;
    size_t bytes = (size_t)out_size * sizeof(float); // 536,870,912
    hipMemsetAsync(out, 0, bytes, stream);           // graph-capturable memset node

    const unsigned int total_threads = (unsigned int)PB * (PD / 2); // 262144
    const int threads = 256;
    rope_scatter_kernel<<<total_threads / threads, threads, 0, stream>>>(out);
}

// Round 5
// 526.205 us; speedup vs baseline: 1.0329x; 1.0329x over previous
//
#include <hip/hip_runtime.h>
#include <math.h>

// Problem constants (setup_inputs: block_size=2048, embedding_dim=256)
#define PB 2048
#define PD 256
#define ROWS_PER_WAVE 8

typedef float f32x4 __attribute__((ext_vector_type(4)));

// theta_i = 10000^(-2*(i-1)/D)  [the (i-1) quirk is intentional, per reference]
//         = exp2( -(i-1) * 2*log2(10000)/256 )
__device__ __forceinline__ float theta_of(int i) {
    const float c = 0.10381025187f; // 2*log2(10000)/256
    return exp2f(-(float)(i - 1) * c);
}

// One wave = 8 consecutive rows (8 KB contiguous). Row R (global, 0..524287):
//   p = R>>8, r = R&255. Lane l owns cols 4l..4l+3 (one dwordx4 = 1 row/64 lanes).
// Even row r=2j nonzeros:  col r-2: sin(p*th_{j-1}) | col r: cos(p*th_min(j,126))
//                          col r+2: -sin(p*th_j)
// Out-of-range j cases (j=0 prev, j=127 next) self-mask: no lane matches the col.
// All transcendentals are wave-uniform per row; per-lane work is pure cndmask.
// R4->R5: 8 rows/wave (store amortization) + branchless native sin/cos.
__global__ __launch_bounds__(256) void rope_build_kernel(float* __restrict__ out) {
    unsigned int wid  = blockIdx.x * 4u + (threadIdx.x >> 6); // global wave id
    int lane = (int)(threadIdx.x & 63u);
    unsigned int row0 = wid * ROWS_PER_WAVE;                  // multiple of 8
    int col0 = 4 * lane;
    f32x4* outq = reinterpret_cast<f32x4*>(out);

    int p  = (int)(row0 >> 8);      // 8 rows never cross a position boundary
    float fp = (float)p;
    int rbase = (int)(row0 & 255u);

    #pragma unroll
    for (int s = 0; s < ROWS_PER_WAVE; ++s) {
        int r = rbase + s;
        f32x4 v = {0.0f, 0.0f, 0.0f, 0.0f};
        if ((s & 1) == 0) { // r even (rbase is a multiple of 8) — compile-time
            int j = r >> 1;
            float c  = __cosf(fp * theta_of(j < 126 ? j : 126));
            float sp = __sinf(fp * theta_of(j - 1)); // unused lanes when j==0
            float sc = -__sinf(fp * theta_of(j));    // unused lanes when j==127
            if ((s & 2) == 0) { // r ≡ 0 (mod 4) — compile-time branch
                v.x = (col0 == r) ? c : 0.0f;
                v.z = (col0 + 2 == r - 2) ? sp : ((col0 + 2 == r + 2) ? sc : 0.0f);
            } else {            // r ≡ 2 (mod 4)
                v.x = (col0 == r - 2) ? sp : ((col0 == r + 2) ? sc : 0.0f);
                v.z = (col0 + 2 == r) ? c : 0.0f;
            }
        }
        outq[(size_t)row0 * 64 + (size_t)s * 64 + lane] = v;
    }
}

extern "C" void kernel_launch(void* const* d_in, const int* in_sizes, int n_in,
                              void* d_out, int out_size, void* d_ws, size_t ws_size,
                              hipStream_t stream) {
    (void)d_in; (void)in_sizes; (void)n_in; (void)d_ws; (void)ws_size;
    float* out = (float*)d_out;
    // total rows = B*D = 524288; waves = rows/8 = 65536; blocks = waves/4
    const unsigned int blocks = (unsigned int)PB * PD / ROWS_PER_WAVE / 4; // 16384
    rope_build_kernel<<<blocks, 256, 0, stream>>>(out);
}

// Round 6
// 508.796 us; speedup vs baseline: 1.0683x; 1.0342x over previous
//
#include <hip/hip_runtime.h>
#include <math.h>

// Problem constants (setup_inputs: block_size=2048, embedding_dim=256)
#define PB 2048
#define PD 256
#define ROWS_PER_WAVE 32  // 8 KB contiguous per wave; 16384 waves total

typedef float f32x4 __attribute__((ext_vector_type(4)));

// theta_i = 10000^(-2*(i-1)/D)  [the (i-1) quirk is intentional, per reference]
__device__ __forceinline__ float theta_of(int i) {
    const float c = 0.10381025187f; // 2*log2(10000)/256
    return exp2f(-(float)(i - 1) * c);
}

// R5->R6: fill-style long-running waves. Each wave = 32 consecutive rows of the
// output (8 KB), looping row stores back-to-back so dozens of dwordx4 stores
// stay in flight per wave (Little's-law fix for the ~3.5 TB/s short-wave
// ceiling seen in R3/R5). Lane l owns cols 4l..4l+3 of each row.
// Even row r=2j nonzeros: col r-2: sin(p*th_{j-1}) | col r: cos(p*th_min(j,126))
//                         col r+2: -sin(p*th_j).  Odd rows all zero.
// sin_{j-1} is carried between even rows -> 2 transcendentals per 2 rows.
__global__ __launch_bounds__(256) void rope_build_kernel(float* __restrict__ out) {
    unsigned int wid = blockIdx.x * 4u + (threadIdx.x >> 6); // 0..16383
    int lane = (int)(threadIdx.x & 63u);
    unsigned int row0 = wid * ROWS_PER_WAVE;                 // multiple of 32
    int col0 = 4 * lane;
    f32x4* outq = reinterpret_cast<f32x4*>(out) + (size_t)row0 * 64 + lane;

    float fp = (float)(int)(row0 >> 8); // position p, uniform over the 32 rows
    int rbase = (int)(row0 & 255u);     // multiple of 32
    int j0 = rbase >> 1;

    float sp = __sinf(fp * theta_of(j0 - 1)); // sin_{j-1} carry (self-masked at j=0)
    const f32x4 zero = {0.0f, 0.0f, 0.0f, 0.0f};

    #pragma unroll
    for (int s = 0; s < ROWS_PER_WAVE; s += 2) {
        int r = rbase + s;      // even row
        int j = r >> 1;
        float sj = __sinf(fp * theta_of(j));
        float c  = __cosf(fp * theta_of(j < 126 ? j : 126));
        f32x4 v = zero;
        if ((s & 2) == 0) { // r ≡ 0 (mod 4) — compile-time after unroll
            v.x = (col0 == r) ? c : 0.0f;
            v.z = (col0 + 2 == r - 2) ? sp : ((col0 + 2 == r + 2) ? -sj : 0.0f);
        } else {            // r ≡ 2 (mod 4)
            v.x = (col0 == r - 2) ? sp : ((col0 == r + 2) ? -sj : 0.0f);
            v.z = (col0 + 2 == r) ? c : 0.0f;
        }
        outq[(size_t)s * 64]       = v;    // even row (1 KB wave store)
        outq[(size_t)(s + 1) * 64] = zero; // odd row, all zeros
        sp = sj;
    }
}

extern "C" void kernel_launch(void* const* d_in, const int* in_sizes, int n_in,
                              void* d_out, int out_size, void* d_ws, size_t ws_size,
                              hipStream_t stream) {
    (void)d_in; (void)in_sizes; (void)n_in; (void)d_ws; (void)ws_size;
    float* out = (float*)d_out;
    // total rows = PB*PD = 524288; waves = 524288/32 = 16384; blocks = 4096
    const unsigned int blocks = (unsigned int)PB * PD / ROWS_PER_WAVE / 4;
    rope_build_kernel<<<blocks, 256, 0, stream>>>(out);
}